// Round 11
// baseline (199.868 us; speedup 1.0000x reference)
//
#include <hip/hip_runtime.h>

typedef __bf16 bf16_t;
typedef __bf16 bf16x8 __attribute__((ext_vector_type(8)));
typedef float  f32x4  __attribute__((ext_vector_type(4)));
typedef unsigned int u32x4 __attribute__((ext_vector_type(4)));

// problem constants
// B=2 C=1280 HEADS=20 DH=64 S=4096 L=77 ENC=4096 GROUPS=32 EPS=1e-5

// ---------------- transpose + fp32->bf16, four matrices in one launch --------
__global__ __launch_bounds__(256) void k_transpose_cvt4(
    const float* __restrict__ w0, const float* __restrict__ w1,
    const float* __restrict__ w2, const float* __restrict__ w3,
    bf16_t* __restrict__ o0, bf16_t* __restrict__ o1,
    bf16_t* __restrict__ o2, bf16_t* __restrict__ o3)
{
  const int z = blockIdx.z;
  const float* in  = (z == 0) ? w0 : (z == 1) ? w1 : (z == 2) ? w2 : w3;
  bf16_t*      out = (z == 0) ? o0 : (z == 1) ? o1 : (z == 2) ? o2 : o3;
  const int R = (z < 2) ? 1280 : 4096;
  const int r0 = blockIdx.y * 64;
  if (r0 >= R) return;
  __shared__ float tile[64][33];
  const int c0 = blockIdx.x * 32;
  const int t = threadIdx.x;
#pragma unroll
  for (int it = 0; it < 8; ++it) {
    int r = it * 8 + (t >> 5), c = t & 31;
    tile[r][c] = in[(size_t)(r0 + r) * 1280 + c0 + c];
  }
  __syncthreads();
  {
    const int oc  = t >> 3;
    const int seg = t & 7;
    bf16x8 o;
#pragma unroll
    for (int e = 0; e < 8; ++e) o[e] = (bf16_t)tile[seg * 8 + e][oc];
    *(bf16x8*)(out + (size_t)(c0 + oc) * R + r0 + seg * 8) = o;
  }
}

// ---------------- GroupNorm partial stats: 32 chunks per (b,g) ----------------
__global__ __launch_bounds__(256) void k_gn_partial(
    const float* __restrict__ x, float* __restrict__ partial)
{
  const int bg    = blockIdx.x >> 5;
  const int chunk = blockIdx.x & 31;
  const float* p  = x + (size_t)bg * 163840 + (size_t)chunk * 5120;
  float s1 = 0.f, s2 = 0.f;
#pragma unroll
  for (int it = 0; it < 5; ++it) {
    float4 v = *(const float4*)(p + (size_t)(it * 256 + threadIdx.x) * 4);
    s1 += v.x + v.y + v.z + v.w;
    s2 += v.x * v.x + v.y * v.y + v.z * v.z + v.w * v.w;
  }
#pragma unroll
  for (int off = 32; off > 0; off >>= 1) {
    s1 += __shfl_down(s1, off);
    s2 += __shfl_down(s2, off);
  }
  __shared__ float r1[4], r2[4];
  if ((threadIdx.x & 63) == 0) { r1[threadIdx.x >> 6] = s1; r2[threadIdx.x >> 6] = s2; }
  __syncthreads();
  if (threadIdx.x == 0) {
    partial[blockIdx.x * 2]     = r1[0] + r1[1] + r1[2] + r1[3];
    partial[blockIdx.x * 2 + 1] = r2[0] + r2[1] + r2[2] + r2[3];
  }
}

// ---------------- finalize: 64 threads, one per (b,g) ----------------
__global__ __launch_bounds__(64) void k_gn_finalize(
    const float* __restrict__ partial, float* __restrict__ stats)
{
  const int bg = threadIdx.x;
  float t1 = 0.f, t2 = 0.f;
#pragma unroll
  for (int c = 0; c < 32; ++c) {
    t1 += partial[(bg * 32 + c) * 2];
    t2 += partial[(bg * 32 + c) * 2 + 1];
  }
  const float invN = 1.0f / 163840.0f;
  float mu  = t1 * invN;
  float var = t2 * invN - mu * mu;
  stats[bg * 2]     = mu;
  stats[bg * 2 + 1] = rsqrtf(var + 1e-5f);
}

// ---------------- GroupNorm apply + transpose -> h (B,S,C) bf16 ----------------
__global__ __launch_bounds__(256) void k_gn_apply(
    const float* __restrict__ x, const float* __restrict__ stats,
    const float* __restrict__ gamma, const float* __restrict__ beta,
    bf16_t* __restrict__ h)
{
  __shared__ float tile[64][65];
  const int s0 = blockIdx.x * 64;
  const int c0 = blockIdx.y * 64;
  const int b  = blockIdx.z;
  const int t  = threadIdx.x;
#pragma unroll
  for (int it = 0; it < 16; ++it) {
    int cl = it * 4 + (t >> 6);
    int sl = t & 63;
    tile[cl][sl] = x[((size_t)(b * 1280 + c0 + cl) << 12) + s0 + sl];
  }
  __syncthreads();
#pragma unroll
  for (int it = 0; it < 2; ++it) {
    int i  = it * 256 + t;
    int sl = i >> 3;
    int cg = i & 7;
    bf16x8 o;
#pragma unroll
    for (int e = 0; e < 8; ++e) {
      int c  = c0 + cg * 8 + e;
      int g  = c / 40;
      float mu = stats[(b * 32 + g) * 2];
      float rs = stats[(b * 32 + g) * 2 + 1];
      o[e] = (bf16_t)((tile[cg * 8 + e][sl] - mu) * rs * gamma[c] + beta[c]);
    }
    *(bf16x8*)(h + (size_t)(b * 4096 + s0 + sl) * 1280 + c0 + cg * 8) = o;
  }
}

// ---------------- LayerNorm(text) -> enc (154,4096) bf16 ----------------
__global__ __launch_bounds__(256) void k_ln(
    const float* __restrict__ text, const float* __restrict__ g,
    const float* __restrict__ bta, bf16_t* __restrict__ enc)
{
  const int row = blockIdx.x;
  const float* p = text + (size_t)row * 4096;
  float s1 = 0.f, s2 = 0.f;
  for (int i = threadIdx.x; i < 1024; i += 256) {
    float4 v = *(const float4*)(p + (size_t)i * 4);
    s1 += v.x + v.y + v.z + v.w;
    s2 += v.x * v.x + v.y * v.y + v.z * v.z + v.w * v.w;
  }
#pragma unroll
  for (int off = 32; off > 0; off >>= 1) {
    s1 += __shfl_down(s1, off);
    s2 += __shfl_down(s2, off);
  }
  __shared__ float r1[4], r2[4], sh[2];
  if ((threadIdx.x & 63) == 0) { r1[threadIdx.x >> 6] = s1; r2[threadIdx.x >> 6] = s2; }
  __syncthreads();
  if (threadIdx.x == 0) {
    float t1 = r1[0] + r1[1] + r1[2] + r1[3];
    float t2 = r2[0] + r2[1] + r2[2] + r2[3];
    const float invN = 1.0f / 4096.0f;
    float mu  = t1 * invN;
    float var = t2 * invN - mu * mu;
    sh[0] = mu;
    sh[1] = rsqrtf(var + 1e-5f);
  }
  __syncthreads();
  const float mu = sh[0], rs = sh[1];
  for (int i = threadIdx.x; i < 1024; i += 256) {
    float4 v  = *(const float4*)(p + (size_t)i * 4);
    float4 gg = *(const float4*)(g + (size_t)i * 4);
    float4 bb = *(const float4*)(bta + (size_t)i * 4);
    bf16_t* o = enc + (size_t)row * 4096 + (size_t)i * 4;
    o[0] = (bf16_t)((v.x - mu) * rs * gg.x + bb.x);
    o[1] = (bf16_t)((v.y - mu) * rs * gg.y + bb.y);
    o[2] = (bf16_t)((v.z - mu) * rs * gg.z + bb.z);
    o[3] = (bf16_t)((v.w - mu) * rs * gg.w + bb.w);
  }
}

// ---------------- 128x64 bf16 MFMA GEMM, BK=32, 5 blocks/CU ------------------
// 2-deep pipeline, 24 KB LDS (2 x (8K A + 4K B)) -> 5 resident blocks/CU with
// grid 1280 = 5/CU exactly: TLP covers the per-step waits. 3 gload_lds/thread/
// tile -> counted vmcnt(3). 64B LDS rows; chunk swizzle c ^= (r^(r>>2))&3
// (self-inverse) applied on GLOBAL source (linear LDS dest, rule #21) and on
// ds_read -> 2-way max bank aliasing (free).
// EPI 0: outb bf16 = acc + bias (LDS-staged 16B stores)      [Q proj]
// EPI 2: dout fp32 = acc + bias + xres, (b,c,s) float4 store [O proj]
template <int EPI>
__global__ __launch_bounds__(256, 5) void k_gemm(
    const bf16_t* __restrict__ A, const bf16_t* __restrict__ BT,
    const float* __restrict__ bias, bf16_t* __restrict__ outb,
    const float* __restrict__ xres, float* __restrict__ dout,
    int lda, int klen, int nnt)
{
  __shared__ alignas(16) bf16_t smem[12288];  // A: 2x4096, B: 2x2048 (24 KB)
  const int tid  = threadIdx.x;
  const int lane = tid & 63;
  const int wv   = tid >> 6;
  const int wm   = wv >> 1, wn = wv & 1;

  const int cpx  = gridDim.x >> 3;
  const int nbid = (blockIdx.x & 7) * cpx + (blockIdx.x >> 3);
  const int mt   = nbid / nnt, ntile = nbid % nnt;
  const int m0   = mt * 128;
  const int n0   = ntile * 64;

  f32x4 acc[4][2];
  const f32x4 fz = {0.f, 0.f, 0.f, 0.f};
#pragma unroll
  for (int i = 0; i < 4; ++i)
#pragma unroll
    for (int j = 0; j < 2; ++j) acc[i][j] = fz;

  // stage one 128x32 A + 64x32 B tile pair (3 gload_lds/thread)
  auto stage = [&](int buf, int kt) {
    bf16_t* sA = smem + buf * 4096;
    bf16_t* sB = smem + 8192 + buf * 2048;
#pragma unroll
    for (int it = 0; it < 2; ++it) {
      int s = it * 256 + tid;
      int row = s >> 2, cs = s & 3;
      const bf16_t* ga =
          A + (size_t)(m0 + row) * lda + kt + ((cs ^ ((row ^ (row >> 2)) & 3)) << 3);
      __builtin_amdgcn_global_load_lds(
          (const __attribute__((address_space(1))) void*)ga,
          (__attribute__((address_space(3))) void*)((char*)sA + s * 16),
          16, 0, 0);
    }
    {
      int s = tid;
      int row = s >> 2, cs = s & 3;
      const bf16_t* gb =
          BT + (size_t)(n0 + row) * lda + kt + ((cs ^ ((row ^ (row >> 2)) & 3)) << 3);
      __builtin_amdgcn_global_load_lds(
          (const __attribute__((address_space(1))) void*)gb,
          (__attribute__((address_space(3))) void*)((char*)sB + s * 16),
          16, 0, 0);
    }
  };

  const int nt_k = klen >> 5;  // BK=32
  stage(0, 0);
  stage(1, 32);

  const int kg = lane >> 4;  // 16B chunk index 0..3
  for (int t = 0; t < nt_k; ++t) {
    if (t + 1 < nt_k) { asm volatile("s_waitcnt vmcnt(3)" ::: "memory"); }
    else              { asm volatile("s_waitcnt vmcnt(0)" ::: "memory"); }
    __builtin_amdgcn_s_barrier();
    const char* pA = (const char*)(smem + (t & 1) * 4096);
    const char* pB = (const char*)(smem + 8192 + (t & 1) * 2048);
    bf16x8 af[4], bfg[2];
#pragma unroll
    for (int i = 0; i < 4; ++i) {
      int r = wm * 64 + i * 16 + (lane & 15);
      af[i] = *(const bf16x8*)(pA + r * 64 + ((kg ^ ((r ^ (r >> 2)) & 3)) << 4));
    }
#pragma unroll
    for (int j = 0; j < 2; ++j) {
      int c = wn * 32 + j * 16 + (lane & 15);
      bfg[j] = *(const bf16x8*)(pB + c * 64 + ((kg ^ ((c ^ (c >> 2)) & 3)) << 4));
    }
#pragma unroll
    for (int i = 0; i < 4; ++i)
#pragma unroll
      for (int j = 0; j < 2; ++j)
        acc[i][j] = __builtin_amdgcn_mfma_f32_16x16x32_bf16(af[i], bfg[j], acc[i][j], 0, 0, 0);
    asm volatile("s_waitcnt lgkmcnt(0)" ::: "memory");
    __builtin_amdgcn_s_barrier();
    if (t + 2 < nt_k) stage(t & 1, (t + 2) * 32);
  }

  if (EPI == 0) {
    bf16_t* cst = smem;  // 128 x 76 bf16 = 19 KB (fits 24 KB)
#pragma unroll
    for (int j = 0; j < 2; ++j) {
      const int n  = n0 + wn * 32 + j * 16 + (lane & 15);
      const float bs = bias[n];
      const int cl = wn * 32 + j * 16 + (lane & 15);
#pragma unroll
      for (int i = 0; i < 4; ++i) {
        const int rl = wm * 64 + i * 16 + ((lane >> 4) << 2);
#pragma unroll
        for (int r = 0; r < 4; ++r)
          cst[(rl + r) * 76 + cl] = (bf16_t)(acc[i][j][r] + bs);
      }
    }
    __syncthreads();
#pragma unroll
    for (int it = 0; it < 4; ++it) {
      int slot = it * 256 + tid;
      int row = slot >> 3, ch = slot & 7;
      u32x4 d = *(const u32x4*)(cst + row * 76 + ch * 8);
      *(u32x4*)(outb + (size_t)(m0 + row) * 1280 + n0 + ch * 8) = d;
    }
  } else {
#pragma unroll
    for (int i = 0; i < 4; ++i) {
      const int mrow = m0 + wm * 64 + i * 16 + ((lane >> 4) << 2);
#pragma unroll
      for (int j = 0; j < 2; ++j) {
        const int n = n0 + wn * 32 + j * 16 + (lane & 15);
        const int b = mrow >> 12, s = mrow & 4095;
        const size_t off = ((size_t)(b * 1280 + n) << 12) + s;
        const float bs = bias[n];
        const float4 xr = *(const float4*)(xres + off);
        float4 o;
        o.x = acc[i][j][0] + bs + xr.x;
        o.y = acc[i][j][1] + bs + xr.y;
        o.z = acc[i][j][2] + bs + xr.z;
        o.w = acc[i][j][3] + bs + xr.w;
        *(float4*)(dout + off) = o;
      }
    }
  }
}

// ---------------- K/V merged projection GEMM (both operands via LDS) ---------
__global__ __launch_bounds__(256, 3) void k_gemm_kv(
    const bf16_t* __restrict__ A, const bf16_t* __restrict__ BT,
    float* __restrict__ outf, int M, int lda, int klen, int nnt, int nst)
{
  __shared__ alignas(16) bf16_t smem[24576];  // 48 KB
  const int tid  = threadIdx.x;
  const int lane = tid & 63;
  const int wv   = tid >> 6;
  const int wm   = wv >> 1, wn = wv & 1;

  const int cpx  = gridDim.x >> 3;
  const int nbid = (blockIdx.x & 7) * cpx + (blockIdx.x >> 3);
  const int mt   = nbid / nnt, ntile = nbid % nnt;
  const int m0   = mt * 128;
  const int n0   = ntile * 64;
  const int kbeg = blockIdx.z * klen;

  f32x4 acc[4][2];
  const f32x4 fz = {0.f, 0.f, 0.f, 0.f};
#pragma unroll
  for (int i = 0; i < 4; ++i)
#pragma unroll
    for (int j = 0; j < 2; ++j) acc[i][j] = fz;

  auto stage = [&](int buf, int kt) {
    bf16_t* sA = smem + buf * 8192;
    bf16_t* sB = smem + 16384 + buf * 4096;
#pragma unroll
    for (int it = 0; it < 4; ++it) {
      int slot = it * 256 + tid;
      int row  = slot >> 3, ch = slot & 7;
      int grow = m0 + row; if (grow > M - 1) grow = M - 1;
      const bf16_t* ga = A + (size_t)grow * lda + kt + ((ch ^ (row & 7)) << 3);
      __builtin_amdgcn_global_load_lds(
          (const __attribute__((address_space(1))) void*)ga,
          (__attribute__((address_space(3))) void*)((char*)sA + slot * 16),
          16, 0, 0);
    }
#pragma unroll
    for (int it = 0; it < 2; ++it) {
      int slot = it * 256 + tid;
      int row  = slot >> 3, ch = slot & 7;
      const bf16_t* gb = BT + (size_t)(n0 + row) * lda + kt + ((ch ^ (row & 7)) << 3);
      __builtin_amdgcn_global_load_lds(
          (const __attribute__((address_space(1))) void*)gb,
          (__attribute__((address_space(3))) void*)((char*)sB + slot * 16),
          16, 0, 0);
    }
  };

  const int nt_k = klen >> 6;
  stage(0, kbeg);
  if (nt_k > 1) stage(1, kbeg + 64);

  for (int t = 0; t < nt_k; ++t) {
    if (t + 1 < nt_k) { asm volatile("s_waitcnt vmcnt(6)" ::: "memory"); }
    else              { asm volatile("s_waitcnt vmcnt(0)" ::: "memory"); }
    __builtin_amdgcn_s_barrier();
    const char* pA = (const char*)(smem + (t & 1) * 8192);
    const char* pB = (const char*)(smem + 16384 + (t & 1) * 4096);
#pragma unroll
    for (int ks = 0; ks < 2; ++ks) {
      const int kb = ks * 64 + ((lane >> 4) << 4);
      bf16x8 af[4], bfg[2];
#pragma unroll
      for (int i = 0; i < 4; ++i) {
        int r = wm * 64 + i * 16 + (lane & 15);
        af[i] = *(const bf16x8*)(pA + r * 128 + (kb ^ ((r & 7) << 4)));
      }
#pragma unroll
      for (int j = 0; j < 2; ++j) {
        int c = wn * 32 + j * 16 + (lane & 15);
        bfg[j] = *(const bf16x8*)(pB + c * 128 + (kb ^ ((c & 7) << 4)));
      }
#pragma unroll
      for (int i = 0; i < 4; ++i)
#pragma unroll
        for (int j = 0; j < 2; ++j)
          acc[i][j] = __builtin_amdgcn_mfma_f32_16x16x32_bf16(af[i], bfg[j], acc[i][j], 0, 0, 0);
    }
    asm volatile("s_waitcnt lgkmcnt(0)" ::: "memory");
    __builtin_amdgcn_s_barrier();
    if (t + 2 < nt_k) stage(t & 1, kbeg + (t + 2) * 64);
  }

#pragma unroll
  for (int i = 0; i < 4; ++i) {
    const int mrow = m0 + wm * 64 + i * 16 + ((lane >> 4) << 2);
#pragma unroll
    for (int j = 0; j < 2; ++j) {
      const int n = n0 + wn * 32 + j * 16 + (lane & 15);
#pragma unroll
      for (int r = 0; r < 4; ++r)
        if (mrow + r < M)
          outf[(size_t)blockIdx.z * 154 * nst + (size_t)(mrow + r) * nst + n] = acc[i][j][r];
    }
  }
}

// ---------------- split-K reduce for merged K/V projections ----------------
__global__ __launch_bounds__(256) void k_kv_reduce(
    const float* __restrict__ part, const float* __restrict__ bk,
    const float* __restrict__ bv, bf16_t* __restrict__ kb, bf16_t* __restrict__ vb)
{
  const int idx = blockIdx.x * 256 + threadIdx.x;  // over 154*2560
  if (idx >= 154 * 2560) return;
  const int r = idx / 2560, n = idx % 2560;
  float s = (n < 1280) ? bk[n] : bv[n - 1280];
#pragma unroll
  for (int sp = 0; sp < 8; ++sp) s += part[(size_t)sp * (154 * 2560) + idx];
  if (n < 1280) kb[(size_t)r * 1280 + n] = (bf16_t)s;
  else          vb[(size_t)r * 1280 + n - 1280] = (bf16_t)s;
}

// ---------------- fused attention (per head, per 64-row s tile) ----------------
__global__ __launch_bounds__(256) void k_attn(
    const bf16_t* __restrict__ q, const bf16_t* __restrict__ kbuf,
    const bf16_t* __restrict__ vbuf, bf16_t* __restrict__ ao,
    const float* __restrict__ size_reg, const int* __restrict__ mask,
    const float* __restrict__ treg)
{
  __shared__ alignas(16) bf16_t sQ[64 * 64];
  __shared__ alignas(16) bf16_t sK[80 * 64];
  __shared__ alignas(16) bf16_t sVT[64 * 104];
  __shared__ alignas(16) bf16_t sP[4 * 16 * 104];
  const int s0   = blockIdx.x * 64;
  const int bh   = blockIdx.y;
  const int b    = bh / 20, head = bh % 20;
  const int tid  = threadIdx.x, lane = tid & 63, wv = tid >> 6;
  const int ntok = lane & 15;

  const u32x4 uz = {0u, 0u, 0u, 0u};
  for (int i = tid; i < 832; i += 256) ((u32x4*)sVT)[i] = uz;
  for (int i = tid; i < 832; i += 256) ((u32x4*)sP)[i]  = uz;

  const size_t qbase = ((size_t)(b * 4096 + s0)) * 1280 + head * 64;
  for (int slot = tid; slot < 512; slot += 256) {
    int row = slot >> 3, ch = slot & 7;
    u32x4 d = *(const u32x4*)(q + qbase + (size_t)row * 1280 + ((ch ^ (row & 7)) << 3));
    *(u32x4*)((char*)sQ + slot * 16) = d;
  }
  const size_t kvbase = ((size_t)(b * 77)) * 1280 + head * 64;
  for (int slot = tid; slot < 640; slot += 256) {
    int tok = slot >> 3, ch = slot & 7;
    u32x4 d = uz;
    if (tok < 77)
      d = *(const u32x4*)(kbuf + kvbase + (size_t)tok * 1280 + ((ch ^ (tok & 7)) << 3));
    *(u32x4*)((char*)sK + slot * 16) = d;
  }
  __syncthreads();
  for (int e = tid; e < 77 * 64; e += 256) {
    int tok = e >> 6, dh = e & 63;
    sVT[dh * 104 + tok] = vbuf[kvbase + (size_t)tok * 1280 + dh];
  }
  __syncthreads();

  f32x4 sim[5];
  const f32x4 fz = {0.f, 0.f, 0.f, 0.f};
#pragma unroll
  for (int nf = 0; nf < 5; ++nf) sim[nf] = fz;
  const int qrow = wv * 16 + (lane & 15);
#pragma unroll
  for (int ks = 0; ks < 2; ++ks) {
    const int kb = ks * 64 + ((lane >> 4) << 4);
    bf16x8 aq = *(const bf16x8*)((const char*)sQ + qrow * 128 + (kb ^ ((qrow & 7) << 4)));
#pragma unroll
    for (int nf = 0; nf < 5; ++nf) {
      int tok = nf * 16 + ntok;
      bf16x8 bk = *(const bf16x8*)((const char*)sK + tok * 128 + (kb ^ ((tok & 7) << 4)));
      sim[nf] = __builtin_amdgcn_mfma_f32_16x16x32_bf16(aq, bk, sim[nf], 0, 0, 0);
    }
  }

  float vv[5][4];
#pragma unroll
  for (int nf = 0; nf < 5; ++nf)
#pragma unroll
    for (int r = 0; r < 4; ++r) vv[nf][r] = sim[nf][r] * 0.125f;

  const int rbase = s0 + wv * 16 + ((lane >> 4) << 2);

  if (b == 1) {
    const float tr = treg[0];
#pragma unroll
    for (int r = 0; r < 4; ++r) {
      float mx = -1e30f, mn = 1e30f;
#pragma unroll
      for (int nf = 0; nf < 5; ++nf)
        if (nf * 16 + ntok < 77) { mx = fmaxf(mx, vv[nf][r]); mn = fminf(mn, vv[nf][r]); }
#pragma unroll
      for (int m = 1; m < 16; m <<= 1) {
        mx = fmaxf(mx, __shfl_xor(mx, m));
        mn = fminf(mn, __shfl_xor(mn, m));
      }
      const int srow = rbase + r;
#pragma unroll
      for (int nf = 0; nf < 5; ++nf) {
        int l = nf * 16 + ntok;
        if (l < 77) {
          float w  = size_reg[srow * 77 + l] * tr;
          int   mk = mask[srow * 77 + l];
          float v  = vv[nf][r];
          vv[nf][r] = (mk > 0) ? v + w * (mx - v) : v - w * (v - mn);
        }
      }
    }
  }

#pragma unroll
  for (int r = 0; r < 4; ++r) {
    float mx = -1e30f;
#pragma unroll
    for (int nf = 0; nf < 5; ++nf)
      if (nf * 16 + ntok < 77) mx = fmaxf(mx, vv[nf][r]);
#pragma unroll
    for (int m = 1; m < 16; m <<= 1) mx = fmaxf(mx, __shfl_xor(mx, m));
    float p[5]; float sm = 0.f;
#pragma unroll
    for (int nf = 0; nf < 5; ++nf) {
      bool val = (nf * 16 + ntok) < 77;
      p[nf] = val ? __expf(vv[nf][r] - mx) : 0.f;
      sm += p[nf];
    }
#pragma unroll
    for (int m = 1; m < 16; m <<= 1) sm += __shfl_xor(sm, m);
    const float inv = 1.0f / sm;
    const int prow = ((lane >> 4) << 2) + r;
#pragma unroll
    for (int nf = 0; nf < 5; ++nf)
      sP[wv * 1664 + prow * 104 + nf * 16 + ntok] = (bf16_t)(p[nf] * inv);
  }
  __syncthreads();

  f32x4 o[4];
#pragma unroll
  for (int fd = 0; fd < 4; ++fd) o[fd] = fz;
#pragma unroll
  for (int ks = 0; ks < 3; ++ks) {
    const int kb = ks * 64 + ((lane >> 4) << 4);
    bf16x8 ap = *(const bf16x8*)((const char*)sP + wv * 3328 + (lane & 15) * 208 + kb);
#pragma unroll
    for (int fd = 0; fd < 4; ++fd) {
      bf16x8 bv = *(const bf16x8*)((const char*)sVT + (fd * 16 + (lane & 15)) * 208 + kb);
      o[fd] = __builtin_amdgcn_mfma_f32_16x16x32_bf16(ap, bv, o[fd], 0, 0, 0);
    }
  }
  const size_t obase =
      ((size_t)(b * 4096 + s0 + wv * 16 + ((lane >> 4) << 2))) * 1280 + head * 64;
#pragma unroll
  for (int fd = 0; fd < 4; ++fd)
#pragma unroll
    for (int r = 0; r < 4; ++r)
      ao[obase + (size_t)r * 1280 + fd * 16 + (lane & 15)] = (bf16_t)o[fd][r];
}

// ---------------- host launch ----------------
extern "C" void kernel_launch(void* const* d_in, const int* in_sizes, int n_in,
                              void* d_out, int out_size, void* d_ws, size_t ws_size,
                              hipStream_t stream)
{
  const float* x    = (const float*)d_in[0];
  const float* text = (const float*)d_in[1];
  const float* gng  = (const float*)d_in[2];
  const float* gnb  = (const float*)d_in[3];
  const float* lng  = (const float*)d_in[4];
  const float* lnb  = (const float*)d_in[5];
  const float* Wq   = (const float*)d_in[6];
  const float* bq   = (const float*)d_in[7];
  const float* Wk   = (const float*)d_in[8];
  const float* bk   = (const float*)d_in[9];
  const float* Wv   = (const float*)d_in[10];
  const float* bv   = (const float*)d_in[11];
  const float* Wo   = (const float*)d_in[12];
  const float* bo   = (const float*)d_in[13];
  const float* sreg = (const float*)d_in[14];
  const float* treg = (const float*)d_in[15];
  const int*   msk  = (const int*)d_in[16];
  float* out = (float*)d_out;

  char* ws = (char*)d_ws;
  size_t off = 0;
  auto alloc = [&](size_t bytes) {
    char* p = ws + off;
    off += (bytes + 255) & ~(size_t)255;
    return p;
  };
  float*  partial = (float*)alloc(2048 * 2 * sizeof(float));
  float*  stats   = (float*)alloc(64 * 2 * sizeof(float));
  bf16_t* WqT = (bf16_t*)alloc((size_t)1280 * 1280 * 2);
  bf16_t* WkT = (bf16_t*)alloc((size_t)1280 * 4096 * 2);  // WvT contiguous after
  bf16_t* WvT = (bf16_t*)alloc((size_t)1280 * 4096 * 2);
  bf16_t* WoT = (bf16_t*)alloc((size_t)1280 * 1280 * 2);
  bf16_t* h   = (bf16_t*)alloc((size_t)8192 * 1280 * 2);  // reused as attn_out
  bf16_t* enc = (bf16_t*)alloc((size_t)154 * 4096 * 2);
  bf16_t* qb  = (bf16_t*)alloc((size_t)8192 * 1280 * 2);
  bf16_t* kb  = (bf16_t*)alloc((size_t)154 * 1280 * 2);
  bf16_t* vb  = (bf16_t*)alloc((size_t)154 * 1280 * 2);
  float*  part = (float*)alloc((size_t)8 * 154 * 2560 * sizeof(float));

  // weight prep: all four transposes in one launch
  k_transpose_cvt4<<<dim3(40, 64, 4), 256, 0, stream>>>(Wq, Wo, Wk, Wv,
                                                        WqT, WoT, WkT, WvT);

  // norms
  k_gn_partial<<<2048, 256, 0, stream>>>(x, partial);
  k_gn_finalize<<<1, 64, 0, stream>>>(partial, stats);
  k_gn_apply<<<dim3(64, 20, 2), 256, 0, stream>>>(x, stats, gng, gnb, h);
  k_ln<<<154, 256, 0, stream>>>(text, lng, lnb, enc);

  // Q projection: M=8192, N=1280 -> grid 64*20 = 1280
  k_gemm<0><<<dim3(1280), 256, 0, stream>>>(h, WqT, bq, qb, nullptr, nullptr,
                                            1280, 1280, 20);
  // merged K+V projection: M=154, N=2560 (WkT||WvT), split-K 8 -> grid 80 x8
  k_gemm_kv<<<dim3(80, 1, 8), 256, 0, stream>>>(enc, WkT, part, 154, 4096, 512, 40, 2560);
  k_kv_reduce<<<1540, 256, 0, stream>>>(part, bk, bv, kb, vb);

  // attention (writes attn_out into h buffer)
  k_attn<<<dim3(64, 40), 256, 0, stream>>>(qb, kb, vb, h, sreg, msk, treg);

  // output projection + residual + transpose to (B,C,S): grid 1280
  k_gemm<2><<<dim3(1280), 256, 0, stream>>>(h, WoT, bo, nullptr, x, out,
                                            1280, 1280, 20);
}

// Round 12
// 165.364 us; speedup vs baseline: 1.2087x; 1.2087x over previous
//
#include <hip/hip_runtime.h>

typedef __bf16 bf16_t;
typedef __bf16 bf16x8 __attribute__((ext_vector_type(8)));
typedef float  f32x4  __attribute__((ext_vector_type(4)));
typedef unsigned int u32x4 __attribute__((ext_vector_type(4)));

// problem constants
// B=2 C=1280 HEADS=20 DH=64 S=4096 L=77 ENC=4096 GROUPS=32 EPS=1e-5

// ---------------- fat prep kernel: 4 transposes + gn_partial + layernorm -----
// blockIdx.x ranges: [0,6720) transposes (z0:800, z1:800, z2:2560, z3:2560),
// [6720,8768) gn_partial (2048), [8768,8922) layernorm rows (154).
__global__ __launch_bounds__(256) void k_prep(
    const float* __restrict__ x, const float* __restrict__ text,
    const float* __restrict__ lng, const float* __restrict__ lnb,
    const float* __restrict__ w0, const float* __restrict__ w1,
    const float* __restrict__ w2, const float* __restrict__ w3,
    bf16_t* __restrict__ o0, bf16_t* __restrict__ o1,
    bf16_t* __restrict__ o2, bf16_t* __restrict__ o3,
    float* __restrict__ partial, bf16_t* __restrict__ enc)
{
  __shared__ float smemf[64 * 33];
  const int bid = blockIdx.x;
  const int t   = threadIdx.x;

  if (bid < 6720) {
    // ---- transpose + cvt: out(C,R) = in(R,C)^T ----
    int z, lb;
    if      (bid < 800)  { z = 0; lb = bid; }
    else if (bid < 1600) { z = 1; lb = bid - 800; }
    else if (bid < 4160) { z = 2; lb = bid - 1600; }
    else                 { z = 3; lb = bid - 4160; }
    const float* in  = (z == 0) ? w0 : (z == 1) ? w1 : (z == 2) ? w2 : w3;
    bf16_t*      out = (z == 0) ? o0 : (z == 1) ? o1 : (z == 2) ? o2 : o3;
    const int R  = (z < 2) ? 1280 : 4096;
    const int c0 = (lb % 40) * 32;
    const int r0 = (lb / 40) * 64;
    float (*tile)[33] = (float(*)[33])smemf;
#pragma unroll
    for (int it = 0; it < 8; ++it) {
      int r = it * 8 + (t >> 5), c = t & 31;
      tile[r][c] = in[(size_t)(r0 + r) * 1280 + c0 + c];
    }
    __syncthreads();
    const int oc  = t >> 3;
    const int seg = t & 7;
    bf16x8 o;
#pragma unroll
    for (int e = 0; e < 8; ++e) o[e] = (bf16_t)tile[seg * 8 + e][oc];
    *(bf16x8*)(out + (size_t)(c0 + oc) * R + r0 + seg * 8) = o;
  } else if (bid < 8768) {
    // ---- GroupNorm partial stats: 32 chunks per (b,g) ----
    const int pb    = bid - 6720;
    const int bg    = pb >> 5;
    const int chunk = pb & 31;
    const float* p  = x + (size_t)bg * 163840 + (size_t)chunk * 5120;
    float s1 = 0.f, s2 = 0.f;
#pragma unroll
    for (int it = 0; it < 5; ++it) {
      float4 v = *(const float4*)(p + (size_t)(it * 256 + t) * 4);
      s1 += v.x + v.y + v.z + v.w;
      s2 += v.x * v.x + v.y * v.y + v.z * v.z + v.w * v.w;
    }
#pragma unroll
    for (int off = 32; off > 0; off >>= 1) {
      s1 += __shfl_down(s1, off);
      s2 += __shfl_down(s2, off);
    }
    float* r1 = smemf;
    float* r2 = smemf + 4;
    if ((t & 63) == 0) { r1[t >> 6] = s1; r2[t >> 6] = s2; }
    __syncthreads();
    if (t == 0) {
      partial[pb * 2]     = r1[0] + r1[1] + r1[2] + r1[3];
      partial[pb * 2 + 1] = r2[0] + r2[1] + r2[2] + r2[3];
    }
  } else {
    // ---- LayerNorm(text) row -> enc bf16 ----
    const int row = bid - 8768;
    const float* p = text + (size_t)row * 4096;
    float s1 = 0.f, s2 = 0.f;
    for (int i = t; i < 1024; i += 256) {
      float4 v = *(const float4*)(p + (size_t)i * 4);
      s1 += v.x + v.y + v.z + v.w;
      s2 += v.x * v.x + v.y * v.y + v.z * v.z + v.w * v.w;
    }
#pragma unroll
    for (int off = 32; off > 0; off >>= 1) {
      s1 += __shfl_down(s1, off);
      s2 += __shfl_down(s2, off);
    }
    float* r1 = smemf;
    float* r2 = smemf + 4;
    float* sh = smemf + 8;
    if ((t & 63) == 0) { r1[t >> 6] = s1; r2[t >> 6] = s2; }
    __syncthreads();
    if (t == 0) {
      float t1 = r1[0] + r1[1] + r1[2] + r1[3];
      float t2 = r2[0] + r2[1] + r2[2] + r2[3];
      const float invN = 1.0f / 4096.0f;
      float mu  = t1 * invN;
      float var = t2 * invN - mu * mu;
      sh[0] = mu;
      sh[1] = rsqrtf(var + 1e-5f);
    }
    __syncthreads();
    const float mu = sh[0], rs = sh[1];
    for (int i = t; i < 1024; i += 256) {
      float4 v  = *(const float4*)(p + (size_t)i * 4);
      float4 gg = *(const float4*)(lng + (size_t)i * 4);
      float4 bb = *(const float4*)(lnb + (size_t)i * 4);
      bf16_t* o = enc + (size_t)row * 4096 + (size_t)i * 4;
      o[0] = (bf16_t)((v.x - mu) * rs * gg.x + bb.x);
      o[1] = (bf16_t)((v.y - mu) * rs * gg.y + bb.y);
      o[2] = (bf16_t)((v.z - mu) * rs * gg.z + bb.z);
      o[3] = (bf16_t)((v.w - mu) * rs * gg.w + bb.w);
    }
  }
}

// ---------------- GroupNorm apply (finalize fused) + transpose -> h ----------
__global__ __launch_bounds__(256) void k_gn_apply(
    const float* __restrict__ x, const float* __restrict__ partial,
    const float* __restrict__ gamma, const float* __restrict__ beta,
    bf16_t* __restrict__ h)
{
  __shared__ float tile[64][65];
  __shared__ float sst[64];  // mu,rs per group
  const int s0 = blockIdx.x * 64;
  const int c0 = blockIdx.y * 64;
  const int b  = blockIdx.z;
  const int t  = threadIdx.x;

  // inline finalize: 8 threads per group, all 32 groups of this batch
  {
    const int g = t >> 3, j = t & 7;
    const int base = ((b * 32 + g) * 32) * 2;
    float s1 = 0.f, s2 = 0.f;
#pragma unroll
    for (int k = 0; k < 4; ++k) {
      s1 += partial[base + (j + 8 * k) * 2];
      s2 += partial[base + (j + 8 * k) * 2 + 1];
    }
    s1 += __shfl_down(s1, 1); s2 += __shfl_down(s2, 1);
    s1 += __shfl_down(s1, 2); s2 += __shfl_down(s2, 2);
    s1 += __shfl_down(s1, 4); s2 += __shfl_down(s2, 4);
    if (j == 0) {
      const float invN = 1.0f / 163840.0f;
      float mu  = s1 * invN;
      float var = s2 * invN - mu * mu;
      sst[g * 2]     = mu;
      sst[g * 2 + 1] = rsqrtf(var + 1e-5f);
    }
  }
#pragma unroll
  for (int it = 0; it < 16; ++it) {
    int cl = it * 4 + (t >> 6);
    int sl = t & 63;
    tile[cl][sl] = x[((size_t)(b * 1280 + c0 + cl) << 12) + s0 + sl];
  }
  __syncthreads();
#pragma unroll
  for (int it = 0; it < 2; ++it) {
    int i  = it * 256 + t;
    int sl = i >> 3;
    int cg = i & 7;
    bf16x8 o;
#pragma unroll
    for (int e = 0; e < 8; ++e) {
      int c  = c0 + cg * 8 + e;
      int g  = c / 40;
      float mu = sst[g * 2];
      float rs = sst[g * 2 + 1];
      o[e] = (bf16_t)((tile[cg * 8 + e][sl] - mu) * rs * gamma[c] + beta[c]);
    }
    *(bf16x8*)(h + (size_t)(b * 4096 + s0 + sl) * 1280 + c0 + cg * 8) = o;
  }
}

// ---------------- 128x64 bf16 MFMA GEMM (round-7 proven config) --------------
// 2-deep pipeline, 48 KB LDS (2 x (16K A + 8K B)), vmcnt(6), 3 blocks/CU,
// XCD-chunk swizzle (gridDim.x % 8 == 0). XOR swizzle pre-applied on GLOBAL
// source (linear LDS dest); ds_read applies the same swizzle.
// EPI 0: outb bf16 = acc + bias (LDS-staged 16B stores)      [Q proj]
// EPI 1: outf fp32 partials, stride nst, offset z*154*nst    [K/V proj merged]
// EPI 2: dout fp32 = acc + bias + xres, (b,c,s) float4 store [O proj]
template <int EPI>
__global__ __launch_bounds__(256, 3) void k_gemm(
    const bf16_t* __restrict__ A, const bf16_t* __restrict__ BT,
    const float* __restrict__ bias, bf16_t* __restrict__ outb,
    float* __restrict__ outf, const float* __restrict__ xres,
    float* __restrict__ dout, int M, int lda, int klen, int nnt, int nst)
{
  __shared__ alignas(16) bf16_t smem[24576];  // 48 KB
  const int tid  = threadIdx.x;
  const int lane = tid & 63;
  const int wv   = tid >> 6;
  const int wm   = wv >> 1, wn = wv & 1;

  const int cpx  = gridDim.x >> 3;
  const int nbid = (blockIdx.x & 7) * cpx + (blockIdx.x >> 3);
  const int mt   = nbid / nnt, ntile = nbid % nnt;
  const int m0   = mt * 128;
  const int n0   = ntile * 64;
  const int kbeg = blockIdx.z * klen;

  f32x4 acc[4][2];
  const f32x4 fz = {0.f, 0.f, 0.f, 0.f};
#pragma unroll
  for (int i = 0; i < 4; ++i)
#pragma unroll
    for (int j = 0; j < 2; ++j) acc[i][j] = fz;

  auto stage = [&](int buf, int kt) {
    bf16_t* sA = smem + buf * 8192;           // A: 128x64
    bf16_t* sB = smem + 16384 + buf * 4096;   // B: 64x64
#pragma unroll
    for (int it = 0; it < 4; ++it) {
      int slot = it * 256 + tid;
      int row  = slot >> 3, ch = slot & 7;
      int grow = m0 + row; if (grow > M - 1) grow = M - 1;
      const bf16_t* ga = A + (size_t)grow * lda + kt + ((ch ^ (row & 7)) << 3);
      __builtin_amdgcn_global_load_lds(
          (const __attribute__((address_space(1))) void*)ga,
          (__attribute__((address_space(3))) void*)((char*)sA + slot * 16),
          16, 0, 0);
    }
#pragma unroll
    for (int it = 0; it < 2; ++it) {
      int slot = it * 256 + tid;
      int row  = slot >> 3, ch = slot & 7;
      const bf16_t* gb = BT + (size_t)(n0 + row) * lda + kt + ((ch ^ (row & 7)) << 3);
      __builtin_amdgcn_global_load_lds(
          (const __attribute__((address_space(1))) void*)gb,
          (__attribute__((address_space(3))) void*)((char*)sB + slot * 16),
          16, 0, 0);
    }
  };

  const int nt_k = klen >> 6;
  stage(0, kbeg);
  if (nt_k > 1) stage(1, kbeg + 64);

  for (int t = 0; t < nt_k; ++t) {
    if (t + 1 < nt_k) { asm volatile("s_waitcnt vmcnt(6)" ::: "memory"); }
    else              { asm volatile("s_waitcnt vmcnt(0)" ::: "memory"); }
    __builtin_amdgcn_s_barrier();
    const char* pA = (const char*)(smem + (t & 1) * 8192);
    const char* pB = (const char*)(smem + 16384 + (t & 1) * 4096);
#pragma unroll
    for (int ks = 0; ks < 2; ++ks) {
      const int kb = ks * 64 + ((lane >> 4) << 4);
      bf16x8 af[4], bfg[2];
#pragma unroll
      for (int i = 0; i < 4; ++i) {
        int r = wm * 64 + i * 16 + (lane & 15);
        af[i] = *(const bf16x8*)(pA + r * 128 + (kb ^ ((r & 7) << 4)));
      }
#pragma unroll
      for (int j = 0; j < 2; ++j) {
        int c = wn * 32 + j * 16 + (lane & 15);
        bfg[j] = *(const bf16x8*)(pB + c * 128 + (kb ^ ((c & 7) << 4)));
      }
#pragma unroll
      for (int i = 0; i < 4; ++i)
#pragma unroll
        for (int j = 0; j < 2; ++j)
          acc[i][j] = __builtin_amdgcn_mfma_f32_16x16x32_bf16(af[i], bfg[j], acc[i][j], 0, 0, 0);
    }
    asm volatile("s_waitcnt lgkmcnt(0)" ::: "memory");
    __builtin_amdgcn_s_barrier();
    if (t + 2 < nt_k) stage(t & 1, kbeg + (t + 2) * 64);
  }

  if (EPI == 0) {
    bf16_t* cst = smem;  // 128 x 76 bf16
#pragma unroll
    for (int j = 0; j < 2; ++j) {
      const int n  = n0 + wn * 32 + j * 16 + (lane & 15);
      const float bs = bias[n];
      const int cl = wn * 32 + j * 16 + (lane & 15);
#pragma unroll
      for (int i = 0; i < 4; ++i) {
        const int rl = wm * 64 + i * 16 + ((lane >> 4) << 2);
#pragma unroll
        for (int r = 0; r < 4; ++r)
          cst[(rl + r) * 76 + cl] = (bf16_t)(acc[i][j][r] + bs);
      }
    }
    __syncthreads();
#pragma unroll
    for (int it = 0; it < 4; ++it) {
      int slot = it * 256 + tid;
      int row = slot >> 3, ch = slot & 7;
      u32x4 d = *(const u32x4*)(cst + row * 76 + ch * 8);
      *(u32x4*)(outb + (size_t)(m0 + row) * 1280 + n0 + ch * 8) = d;
    }
  } else {
#pragma unroll
    for (int i = 0; i < 4; ++i) {
      const int mrow = m0 + wm * 64 + i * 16 + ((lane >> 4) << 2);
#pragma unroll
      for (int j = 0; j < 2; ++j) {
        const int n = n0 + wn * 32 + j * 16 + (lane & 15);
        if (EPI == 2) {
          const int b = mrow >> 12, s = mrow & 4095;
          const size_t off = ((size_t)(b * 1280 + n) << 12) + s;
          const float bs = bias[n];
          const float4 xr = *(const float4*)(xres + off);
          float4 o;
          o.x = acc[i][j][0] + bs + xr.x;
          o.y = acc[i][j][1] + bs + xr.y;
          o.z = acc[i][j][2] + bs + xr.z;
          o.w = acc[i][j][3] + bs + xr.w;
          *(float4*)(dout + off) = o;
        } else {
#pragma unroll
          for (int r = 0; r < 4; ++r)
            if (mrow + r < M)
              outf[(size_t)blockIdx.z * 154 * nst + (size_t)(mrow + r) * nst + n] = acc[i][j][r];
        }
      }
    }
  }
}

// ---------------- split-K reduce for merged K/V projections (float4) ---------
// part: [8][154][2560] fp32 ; cols 0..1279 -> kb, 1280..2559 -> vb
__global__ __launch_bounds__(256) void k_kv_reduce(
    const float* __restrict__ part, const float* __restrict__ bk,
    const float* __restrict__ bv, bf16_t* __restrict__ kb, bf16_t* __restrict__ vb)
{
  const int i4 = (blockIdx.x * 256 + threadIdx.x) * 4;  // over 154*2560
  if (i4 >= 154 * 2560) return;
  const int r = i4 / 2560, n = i4 % 2560;  // n..n+3 same row, same half
  float4 s = (n < 1280) ? *(const float4*)(bk + n) : *(const float4*)(bv + n - 1280);
#pragma unroll
  for (int sp = 0; sp < 8; ++sp) {
    float4 p = *(const float4*)(part + (size_t)sp * (154 * 2560) + i4);
    s.x += p.x; s.y += p.y; s.z += p.z; s.w += p.w;
  }
  bf16_t* dst = (n < 1280) ? (kb + (size_t)r * 1280 + n) : (vb + (size_t)r * 1280 + n - 1280);
  dst[0] = (bf16_t)s.x; dst[1] = (bf16_t)s.y; dst[2] = (bf16_t)s.z; dst[3] = (bf16_t)s.w;
}

// ---------------- fused attention (per head, per 64-row s tile) ----------------
__global__ __launch_bounds__(256) void k_attn(
    const bf16_t* __restrict__ q, const bf16_t* __restrict__ kbuf,
    const bf16_t* __restrict__ vbuf, bf16_t* __restrict__ ao,
    const float* __restrict__ size_reg, const int* __restrict__ mask,
    const float* __restrict__ treg)
{
  __shared__ alignas(16) bf16_t sQ[64 * 64];
  __shared__ alignas(16) bf16_t sK[80 * 64];
  __shared__ alignas(16) bf16_t sVT[64 * 104];
  __shared__ alignas(16) bf16_t sP[4 * 16 * 104];
  const int s0   = blockIdx.x * 64;
  const int bh   = blockIdx.y;
  const int b    = bh / 20, head = bh % 20;
  const int tid  = threadIdx.x, lane = tid & 63, wv = tid >> 6;
  const int ntok = lane & 15;

  const u32x4 uz = {0u, 0u, 0u, 0u};
  for (int i = tid; i < 832; i += 256) ((u32x4*)sVT)[i] = uz;
  for (int i = tid; i < 832; i += 256) ((u32x4*)sP)[i]  = uz;

  const size_t qbase = ((size_t)(b * 4096 + s0)) * 1280 + head * 64;
  for (int slot = tid; slot < 512; slot += 256) {
    int row = slot >> 3, ch = slot & 7;
    u32x4 d = *(const u32x4*)(q + qbase + (size_t)row * 1280 + ((ch ^ (row & 7)) << 3));
    *(u32x4*)((char*)sQ + slot * 16) = d;
  }
  const size_t kvbase = ((size_t)(b * 77)) * 1280 + head * 64;
  for (int slot = tid; slot < 640; slot += 256) {
    int tok = slot >> 3, ch = slot & 7;
    u32x4 d = uz;
    if (tok < 77)
      d = *(const u32x4*)(kbuf + kvbase + (size_t)tok * 1280 + ((ch ^ (tok & 7)) << 3));
    *(u32x4*)((char*)sK + slot * 16) = d;
  }
  __syncthreads();
  for (int e = tid; e < 77 * 64; e += 256) {
    int tok = e >> 6, dh = e & 63;
    sVT[dh * 104 + tok] = vbuf[kvbase + (size_t)tok * 1280 + dh];
  }
  __syncthreads();

  f32x4 sim[5];
  const f32x4 fz = {0.f, 0.f, 0.f, 0.f};
#pragma unroll
  for (int nf = 0; nf < 5; ++nf) sim[nf] = fz;
  const int qrow = wv * 16 + (lane & 15);
#pragma unroll
  for (int ks = 0; ks < 2; ++ks) {
    const int kb = ks * 64 + ((lane >> 4) << 4);
    bf16x8 aq = *(const bf16x8*)((const char*)sQ + qrow * 128 + (kb ^ ((qrow & 7) << 4)));
#pragma unroll
    for (int nf = 0; nf < 5; ++nf) {
      int tok = nf * 16 + ntok;
      bf16x8 bk = *(const bf16x8*)((const char*)sK + tok * 128 + (kb ^ ((tok & 7) << 4)));
      sim[nf] = __builtin_amdgcn_mfma_f32_16x16x32_bf16(aq, bk, sim[nf], 0, 0, 0);
    }
  }

  float vv[5][4];
#pragma unroll
  for (int nf = 0; nf < 5; ++nf)
#pragma unroll
    for (int r = 0; r < 4; ++r) vv[nf][r] = sim[nf][r] * 0.125f;

  const int rbase = s0 + wv * 16 + ((lane >> 4) << 2);

  if (b == 1) {
    const float tr = treg[0];
#pragma unroll
    for (int r = 0; r < 4; ++r) {
      float mx = -1e30f, mn = 1e30f;
#pragma unroll
      for (int nf = 0; nf < 5; ++nf)
        if (nf * 16 + ntok < 77) { mx = fmaxf(mx, vv[nf][r]); mn = fminf(mn, vv[nf][r]); }
#pragma unroll
      for (int m = 1; m < 16; m <<= 1) {
        mx = fmaxf(mx, __shfl_xor(mx, m));
        mn = fminf(mn, __shfl_xor(mn, m));
      }
      const int srow = rbase + r;
#pragma unroll
      for (int nf = 0; nf < 5; ++nf) {
        int l = nf * 16 + ntok;
        if (l < 77) {
          float w  = size_reg[srow * 77 + l] * tr;
          int   mk = mask[srow * 77 + l];
          float v  = vv[nf][r];
          vv[nf][r] = (mk > 0) ? v + w * (mx - v) : v - w * (v - mn);
        }
      }
    }
  }

#pragma unroll
  for (int r = 0; r < 4; ++r) {
    float mx = -1e30f;
#pragma unroll
    for (int nf = 0; nf < 5; ++nf)
      if (nf * 16 + ntok < 77) mx = fmaxf(mx, vv[nf][r]);
#pragma unroll
    for (int m = 1; m < 16; m <<= 1) mx = fmaxf(mx, __shfl_xor(mx, m));
    float p[5]; float sm = 0.f;
#pragma unroll
    for (int nf = 0; nf < 5; ++nf) {
      bool val = (nf * 16 + ntok) < 77;
      p[nf] = val ? __expf(vv[nf][r] - mx) : 0.f;
      sm += p[nf];
    }
#pragma unroll
    for (int m = 1; m < 16; m <<= 1) sm += __shfl_xor(sm, m);
    const float inv = 1.0f / sm;
    const int prow = ((lane >> 4) << 2) + r;
#pragma unroll
    for (int nf = 0; nf < 5; ++nf)
      sP[wv * 1664 + prow * 104 + nf * 16 + ntok] = (bf16_t)(p[nf] * inv);
  }
  __syncthreads();

  f32x4 o[4];
#pragma unroll
  for (int fd = 0; fd < 4; ++fd) o[fd] = fz;
#pragma unroll
  for (int ks = 0; ks < 3; ++ks) {
    const int kb = ks * 64 + ((lane >> 4) << 4);
    bf16x8 ap = *(const bf16x8*)((const char*)sP + wv * 3328 + (lane & 15) * 208 + kb);
#pragma unroll
    for (int fd = 0; fd < 4; ++fd) {
      bf16x8 bv = *(const bf16x8*)((const char*)sVT + (fd * 16 + (lane & 15)) * 208 + kb);
      o[fd] = __builtin_amdgcn_mfma_f32_16x16x32_bf16(ap, bv, o[fd], 0, 0, 0);
    }
  }
  const size_t obase =
      ((size_t)(b * 4096 + s0 + wv * 16 + ((lane >> 4) << 2))) * 1280 + head * 64;
#pragma unroll
  for (int fd = 0; fd < 4; ++fd)
#pragma unroll
    for (int r = 0; r < 4; ++r)
      ao[obase + (size_t)r * 1280 + fd * 16 + (lane & 15)] = (bf16_t)o[fd][r];
}

// ---------------- host launch ----------------
extern "C" void kernel_launch(void* const* d_in, const int* in_sizes, int n_in,
                              void* d_out, int out_size, void* d_ws, size_t ws_size,
                              hipStream_t stream)
{
  const float* x    = (const float*)d_in[0];
  const float* text = (const float*)d_in[1];
  const float* gng  = (const float*)d_in[2];
  const float* gnb  = (const float*)d_in[3];
  const float* lng  = (const float*)d_in[4];
  const float* lnb  = (const float*)d_in[5];
  const float* Wq   = (const float*)d_in[6];
  const float* bq   = (const float*)d_in[7];
  const float* Wk   = (const float*)d_in[8];
  const float* bk   = (const float*)d_in[9];
  const float* Wv   = (const float*)d_in[10];
  const float* bv   = (const float*)d_in[11];
  const float* Wo   = (const float*)d_in[12];
  const float* bo   = (const float*)d_in[13];
  const float* sreg = (const float*)d_in[14];
  const float* treg = (const float*)d_in[15];
  const int*   msk  = (const int*)d_in[16];
  float* out = (float*)d_out;

  char* ws = (char*)d_ws;
  size_t off = 0;
  auto alloc = [&](size_t bytes) {
    char* p = ws + off;
    off += (bytes + 255) & ~(size_t)255;
    return p;
  };
  float*  partial = (float*)alloc(2048 * 2 * sizeof(float));
  bf16_t* WqT = (bf16_t*)alloc((size_t)1280 * 1280 * 2);
  bf16_t* WkT = (bf16_t*)alloc((size_t)1280 * 4096 * 2);  // WvT contiguous after
  bf16_t* WvT = (bf16_t*)alloc((size_t)1280 * 4096 * 2);
  bf16_t* WoT = (bf16_t*)alloc((size_t)1280 * 1280 * 2);
  bf16_t* h   = (bf16_t*)alloc((size_t)8192 * 1280 * 2);  // reused as attn_out
  bf16_t* enc = (bf16_t*)alloc((size_t)154 * 4096 * 2);
  bf16_t* qb  = (bf16_t*)alloc((size_t)8192 * 1280 * 2);
  bf16_t* kb  = (bf16_t*)alloc((size_t)154 * 1280 * 2);
  bf16_t* vb  = (bf16_t*)alloc((size_t)154 * 1280 * 2);
  float*  part = (float*)alloc((size_t)8 * 154 * 2560 * sizeof(float));

  // prep: 4 weight transposes + gn_partial + layernorm in ONE launch
  k_prep<<<8922, 256, 0, stream>>>(x, text, lng, lnb, Wq, Wo, Wk, Wv,
                                   WqT, WoT, WkT, WvT, partial, enc);

  // gn apply (finalize fused)
  k_gn_apply<<<dim3(64, 20, 2), 256, 0, stream>>>(x, partial, gng, gnb, h);

  // Q projection: M=8192, N=1280 -> grid 64*20 = 1280
  k_gemm<0><<<dim3(1280), 256, 0, stream>>>(h, WqT, bq, qb, nullptr, nullptr, nullptr,
                                            8192, 1280, 1280, 20, 1280);
  // merged K+V projection: M=154, N=2560 (WkT||WvT), split-K 8 -> grid 80 x8
  k_gemm<1><<<dim3(80, 1, 8), 256, 0, stream>>>(enc, WkT, nullptr, nullptr, part, nullptr, nullptr,
                                                154, 4096, 512, 40, 2560);
  k_kv_reduce<<<385, 256, 0, stream>>>(part, bk, bv, kb, vb);

  // attention (writes attn_out into h buffer)
  k_attn<<<dim3(64, 40), 256, 0, stream>>>(qb, kb, vb, h, sreg, msk, treg);

  // output projection + residual + transpose to (B,C,S): grid 1280
  k_gemm<2><<<dim3(1280), 256, 0, stream>>>(h, WoT, bo, nullptr, nullptr, x, out,
                                            8192, 1280, 1280, 20, 1280);
}

// Round 14
// 159.940 us; speedup vs baseline: 1.2496x; 1.0339x over previous
//
#include <hip/hip_runtime.h>

typedef __bf16 bf16_t;
typedef __bf16 bf16x8 __attribute__((ext_vector_type(8)));
typedef float  f32x4  __attribute__((ext_vector_type(4)));
typedef unsigned int u32x4 __attribute__((ext_vector_type(4)));

// problem constants
// B=2 C=1280 HEADS=20 DH=64 S=4096 L=77 ENC=4096 GROUPS=32 EPS=1e-5

// ---------------- fat prep kernel: 4 transposes + gn_partial + layernorm -----
__global__ __launch_bounds__(256) void k_prep(
    const float* __restrict__ x, const float* __restrict__ text,
    const float* __restrict__ lng, const float* __restrict__ lnb,
    const float* __restrict__ w0, const float* __restrict__ w1,
    const float* __restrict__ w2, const float* __restrict__ w3,
    bf16_t* __restrict__ o0, bf16_t* __restrict__ o1,
    bf16_t* __restrict__ o2, bf16_t* __restrict__ o3,
    float* __restrict__ partial, bf16_t* __restrict__ enc)
{
  __shared__ float smemf[64 * 33];
  const int bid = blockIdx.x;
  const int t   = threadIdx.x;

  if (bid < 6720) {
    int z, lb;
    if      (bid < 800)  { z = 0; lb = bid; }
    else if (bid < 1600) { z = 1; lb = bid - 800; }
    else if (bid < 4160) { z = 2; lb = bid - 1600; }
    else                 { z = 3; lb = bid - 4160; }
    const float* in  = (z == 0) ? w0 : (z == 1) ? w1 : (z == 2) ? w2 : w3;
    bf16_t*      out = (z == 0) ? o0 : (z == 1) ? o1 : (z == 2) ? o2 : o3;
    const int R  = (z < 2) ? 1280 : 4096;
    const int c0 = (lb % 40) * 32;
    const int r0 = (lb / 40) * 64;
    float (*tile)[33] = (float(*)[33])smemf;
#pragma unroll
    for (int it = 0; it < 8; ++it) {
      int r = it * 8 + (t >> 5), c = t & 31;
      tile[r][c] = in[(size_t)(r0 + r) * 1280 + c0 + c];
    }
    __syncthreads();
    const int oc  = t >> 3;
    const int seg = t & 7;
    bf16x8 o;
#pragma unroll
    for (int e = 0; e < 8; ++e) o[e] = (bf16_t)tile[seg * 8 + e][oc];
    *(bf16x8*)(out + (size_t)(c0 + oc) * R + r0 + seg * 8) = o;
  } else if (bid < 8768) {
    const int pb    = bid - 6720;
    const int bg    = pb >> 5;
    const int chunk = pb & 31;
    const float* p  = x + (size_t)bg * 163840 + (size_t)chunk * 5120;
    float s1 = 0.f, s2 = 0.f;
#pragma unroll
    for (int it = 0; it < 5; ++it) {
      float4 v = *(const float4*)(p + (size_t)(it * 256 + t) * 4);
      s1 += v.x + v.y + v.z + v.w;
      s2 += v.x * v.x + v.y * v.y + v.z * v.z + v.w * v.w;
    }
#pragma unroll
    for (int off = 32; off > 0; off >>= 1) {
      s1 += __shfl_down(s1, off);
      s2 += __shfl_down(s2, off);
    }
    float* r1 = smemf;
    float* r2 = smemf + 4;
    if ((t & 63) == 0) { r1[t >> 6] = s1; r2[t >> 6] = s2; }
    __syncthreads();
    if (t == 0) {
      partial[pb * 2]     = r1[0] + r1[1] + r1[2] + r1[3];
      partial[pb * 2 + 1] = r2[0] + r2[1] + r2[2] + r2[3];
    }
  } else {
    const int row = bid - 8768;
    const float* p = text + (size_t)row * 4096;
    float s1 = 0.f, s2 = 0.f;
    for (int i = t; i < 1024; i += 256) {
      float4 v = *(const float4*)(p + (size_t)i * 4);
      s1 += v.x + v.y + v.z + v.w;
      s2 += v.x * v.x + v.y * v.y + v.z * v.z + v.w * v.w;
    }
#pragma unroll
    for (int off = 32; off > 0; off >>= 1) {
      s1 += __shfl_down(s1, off);
      s2 += __shfl_down(s2, off);
    }
    float* r1 = smemf;
    float* r2 = smemf + 4;
    float* sh = smemf + 8;
    if ((t & 63) == 0) { r1[t >> 6] = s1; r2[t >> 6] = s2; }
    __syncthreads();
    if (t == 0) {
      float t1 = r1[0] + r1[1] + r1[2] + r1[3];
      float t2 = r2[0] + r2[1] + r2[2] + r2[3];
      const float invN = 1.0f / 4096.0f;
      float mu  = t1 * invN;
      float var = t2 * invN - mu * mu;
      sh[0] = mu;
      sh[1] = rsqrtf(var + 1e-5f);
    }
    __syncthreads();
    const float mu = sh[0], rs = sh[1];
    for (int i = t; i < 1024; i += 256) {
      float4 v  = *(const float4*)(p + (size_t)i * 4);
      float4 gg = *(const float4*)(lng + (size_t)i * 4);
      float4 bb = *(const float4*)(lnb + (size_t)i * 4);
      bf16_t* o = enc + (size_t)row * 4096 + (size_t)i * 4;
      o[0] = (bf16_t)((v.x - mu) * rs * gg.x + bb.x);
      o[1] = (bf16_t)((v.y - mu) * rs * gg.y + bb.y);
      o[2] = (bf16_t)((v.z - mu) * rs * gg.z + bb.z);
      o[3] = (bf16_t)((v.w - mu) * rs * gg.w + bb.w);
    }
  }
}

// ---------------- GroupNorm apply (finalize fused) + transpose -> h ----------
__global__ __launch_bounds__(256) void k_gn_apply(
    const float* __restrict__ x, const float* __restrict__ partial,
    const float* __restrict__ gamma, const float* __restrict__ beta,
    bf16_t* __restrict__ h)
{
  __shared__ float tile[64][65];
  __shared__ float sst[64];
  const int s0 = blockIdx.x * 64;
  const int c0 = blockIdx.y * 64;
  const int b  = blockIdx.z;
  const int t  = threadIdx.x;

  {
    const int g = t >> 3, j = t & 7;
    const int base = ((b * 32 + g) * 32) * 2;
    float s1 = 0.f, s2 = 0.f;
#pragma unroll
    for (int k = 0; k < 4; ++k) {
      s1 += partial[base + (j + 8 * k) * 2];
      s2 += partial[base + (j + 8 * k) * 2 + 1];
    }
    s1 += __shfl_down(s1, 1); s2 += __shfl_down(s2, 1);
    s1 += __shfl_down(s1, 2); s2 += __shfl_down(s2, 2);
    s1 += __shfl_down(s1, 4); s2 += __shfl_down(s2, 4);
    if (j == 0) {
      const float invN = 1.0f / 163840.0f;
      float mu  = s1 * invN;
      float var = s2 * invN - mu * mu;
      sst[g * 2]     = mu;
      sst[g * 2 + 1] = rsqrtf(var + 1e-5f);
    }
  }
#pragma unroll
  for (int it = 0; it < 16; ++it) {
    int cl = it * 4 + (t >> 6);
    int sl = t & 63;
    tile[cl][sl] = x[((size_t)(b * 1280 + c0 + cl) << 12) + s0 + sl];
  }
  __syncthreads();
#pragma unroll
  for (int it = 0; it < 2; ++it) {
    int i  = it * 256 + t;
    int sl = i >> 3;
    int cg = i & 7;
    bf16x8 o;
#pragma unroll
    for (int e = 0; e < 8; ++e) {
      int c  = c0 + cg * 8 + e;
      int g  = c / 40;
      float mu = sst[g * 2];
      float rs = sst[g * 2 + 1];
      o[e] = (bf16_t)((tile[cg * 8 + e][sl] - mu) * rs * gamma[c] + beta[c]);
    }
    *(bf16x8*)(h + (size_t)(b * 4096 + s0 + sl) * 1280 + c0 + cg * 8) = o;
  }
}

// ---------------- merged Q-proj + K/V-proj GEMM (one launch, 1920 blocks) ----
// blocks [0,1280): Q-proj  — A=h (8192x1280), BT=WqT, EPI0 (bf16 + bias)
// blocks [1280,1920): K/V  — A=enc (154x4096), BT=WkT||WvT, split-K 8, EPI1
// Round-7/12 proven inner loop: 2-deep gload_lds dbuf, vmcnt(6), 48 KB LDS,
// row&7 chunk swizzle pre-applied on GLOBAL source (linear LDS dest).
__global__ __launch_bounds__(256, 3) void k_gemm_qkv(
    const bf16_t* __restrict__ h, const bf16_t* __restrict__ WqT,
    const float* __restrict__ bq, bf16_t* __restrict__ qb,
    const bf16_t* __restrict__ enc, const bf16_t* __restrict__ WkT,
    float* __restrict__ part)
{
  __shared__ alignas(16) bf16_t smem[24576];  // 48 KB
  const int tid  = threadIdx.x;
  const int lane = tid & 63;
  const int wv   = tid >> 6;
  const int wm   = wv >> 1, wn = wv & 1;

  const bool isKV = blockIdx.x >= 1280;
  const bf16_t* A;
  const bf16_t* BT;
  int M, lda, kbeg, klen, m0, n0, sk = 0;
  if (!isKV) {
    const int nbid = (blockIdx.x & 7) * 160 + (blockIdx.x >> 3);
    m0 = (nbid / 20) * 128;
    n0 = (nbid % 20) * 64;
    A = h; BT = WqT; M = 8192; lda = 1280; kbeg = 0; klen = 1280;
  } else {
    const int xx = blockIdx.x - 1280;
    sk = xx / 80;
    const int tl = xx % 80;
    const int nb = (tl & 7) * 10 + (tl >> 3);
    m0 = (nb / 40) * 128;
    n0 = (nb % 40) * 64;
    A = enc; BT = WkT; M = 154; lda = 4096; kbeg = sk * 512; klen = 512;
  }

  f32x4 acc[4][2];
  const f32x4 fz = {0.f, 0.f, 0.f, 0.f};
#pragma unroll
  for (int i = 0; i < 4; ++i)
#pragma unroll
    for (int j = 0; j < 2; ++j) acc[i][j] = fz;

  auto stage = [&](int buf, int kt) {
    bf16_t* sA = smem + buf * 8192;           // A: 128x64
    bf16_t* sB = smem + 16384 + buf * 4096;   // B: 64x64
#pragma unroll
    for (int it = 0; it < 4; ++it) {
      int slot = it * 256 + tid;
      int row  = slot >> 3, ch = slot & 7;
      int grow = m0 + row; if (grow > M - 1) grow = M - 1;
      const bf16_t* ga = A + (size_t)grow * lda + kt + ((ch ^ (row & 7)) << 3);
      __builtin_amdgcn_global_load_lds(
          (const __attribute__((address_space(1))) void*)ga,
          (__attribute__((address_space(3))) void*)((char*)sA + slot * 16),
          16, 0, 0);
    }
#pragma unroll
    for (int it = 0; it < 2; ++it) {
      int slot = it * 256 + tid;
      int row  = slot >> 3, ch = slot & 7;
      const bf16_t* gb = BT + (size_t)(n0 + row) * lda + kt + ((ch ^ (row & 7)) << 3);
      __builtin_amdgcn_global_load_lds(
          (const __attribute__((address_space(1))) void*)gb,
          (__attribute__((address_space(3))) void*)((char*)sB + slot * 16),
          16, 0, 0);
    }
  };

  const int nt_k = klen >> 6;
  stage(0, kbeg);
  stage(1, kbeg + 64);

  for (int t = 0; t < nt_k; ++t) {
    if (t + 1 < nt_k) { asm volatile("s_waitcnt vmcnt(6)" ::: "memory"); }
    else              { asm volatile("s_waitcnt vmcnt(0)" ::: "memory"); }
    __builtin_amdgcn_s_barrier();
    const char* pA = (const char*)(smem + (t & 1) * 8192);
    const char* pB = (const char*)(smem + 16384 + (t & 1) * 4096);
#pragma unroll
    for (int ks = 0; ks < 2; ++ks) {
      const int kb = ks * 64 + ((lane >> 4) << 4);
      bf16x8 af[4], bfg[2];
#pragma unroll
      for (int i = 0; i < 4; ++i) {
        int r = wm * 64 + i * 16 + (lane & 15);
        af[i] = *(const bf16x8*)(pA + r * 128 + (kb ^ ((r & 7) << 4)));
      }
#pragma unroll
      for (int j = 0; j < 2; ++j) {
        int c = wn * 32 + j * 16 + (lane & 15);
        bfg[j] = *(const bf16x8*)(pB + c * 128 + (kb ^ ((c & 7) << 4)));
      }
#pragma unroll
      for (int i = 0; i < 4; ++i)
#pragma unroll
        for (int j = 0; j < 2; ++j)
          acc[i][j] = __builtin_amdgcn_mfma_f32_16x16x32_bf16(af[i], bfg[j], acc[i][j], 0, 0, 0);
    }
    asm volatile("s_waitcnt lgkmcnt(0)" ::: "memory");
    __builtin_amdgcn_s_barrier();
    if (t + 2 < nt_k) stage(t & 1, kbeg + (t + 2) * 64);
  }

  if (!isKV) {
    bf16_t* cst = smem;  // 128 x 76 bf16
#pragma unroll
    for (int j = 0; j < 2; ++j) {
      const int n  = n0 + wn * 32 + j * 16 + (lane & 15);
      const float bs = bq[n];
      const int cl = wn * 32 + j * 16 + (lane & 15);
#pragma unroll
      for (int i = 0; i < 4; ++i) {
        const int rl = wm * 64 + i * 16 + ((lane >> 4) << 2);
#pragma unroll
        for (int r = 0; r < 4; ++r)
          cst[(rl + r) * 76 + cl] = (bf16_t)(acc[i][j][r] + bs);
      }
    }
    __syncthreads();
#pragma unroll
    for (int it = 0; it < 4; ++it) {
      int slot = it * 256 + tid;
      int row = slot >> 3, ch = slot & 7;
      u32x4 d = *(const u32x4*)(cst + row * 76 + ch * 8);
      *(u32x4*)(qb + (size_t)(m0 + row) * 1280 + n0 + ch * 8) = d;
    }
  } else {
#pragma unroll
    for (int i = 0; i < 4; ++i) {
      const int mrow = m0 + wm * 64 + i * 16 + ((lane >> 4) << 2);
#pragma unroll
      for (int j = 0; j < 2; ++j) {
        const int n = n0 + wn * 32 + j * 16 + (lane & 15);
#pragma unroll
        for (int r = 0; r < 4; ++r)
          if (mrow + r < 154)
            part[(size_t)sk * (154 * 2560) + (size_t)(mrow + r) * 2560 + n] = acc[i][j][r];
      }
    }
  }
}

// ---------------- O-proj GEMM (round-7/12 proven, EPI2) ----------------------
__global__ __launch_bounds__(256, 3) void k_gemm_o(
    const bf16_t* __restrict__ A, const bf16_t* __restrict__ BT,
    const float* __restrict__ bias, const float* __restrict__ xres,
    float* __restrict__ dout)
{
  __shared__ alignas(16) bf16_t smem[24576];
  const int tid  = threadIdx.x;
  const int lane = tid & 63;
  const int wv   = tid >> 6;
  const int wm   = wv >> 1, wn = wv & 1;

  const int nbid = (blockIdx.x & 7) * 160 + (blockIdx.x >> 3);
  const int m0   = (nbid / 20) * 128;
  const int n0   = (nbid % 20) * 64;
  const int lda  = 1280;

  f32x4 acc[4][2];
  const f32x4 fz = {0.f, 0.f, 0.f, 0.f};
#pragma unroll
  for (int i = 0; i < 4; ++i)
#pragma unroll
    for (int j = 0; j < 2; ++j) acc[i][j] = fz;

  auto stage = [&](int buf, int kt) {
    bf16_t* sA = smem + buf * 8192;
    bf16_t* sB = smem + 16384 + buf * 4096;
#pragma unroll
    for (int it = 0; it < 4; ++it) {
      int slot = it * 256 + tid;
      int row  = slot >> 3, ch = slot & 7;
      const bf16_t* ga = A + (size_t)(m0 + row) * lda + kt + ((ch ^ (row & 7)) << 3);
      __builtin_amdgcn_global_load_lds(
          (const __attribute__((address_space(1))) void*)ga,
          (__attribute__((address_space(3))) void*)((char*)sA + slot * 16),
          16, 0, 0);
    }
#pragma unroll
    for (int it = 0; it < 2; ++it) {
      int slot = it * 256 + tid;
      int row  = slot >> 3, ch = slot & 7;
      const bf16_t* gb = BT + (size_t)(n0 + row) * lda + kt + ((ch ^ (row & 7)) << 3);
      __builtin_amdgcn_global_load_lds(
          (const __attribute__((address_space(1))) void*)gb,
          (__attribute__((address_space(3))) void*)((char*)sB + slot * 16),
          16, 0, 0);
    }
  };

  const int nt_k = 20;
  stage(0, 0);
  stage(1, 64);

  for (int t = 0; t < nt_k; ++t) {
    if (t + 1 < nt_k) { asm volatile("s_waitcnt vmcnt(6)" ::: "memory"); }
    else              { asm volatile("s_waitcnt vmcnt(0)" ::: "memory"); }
    __builtin_amdgcn_s_barrier();
    const char* pA = (const char*)(smem + (t & 1) * 8192);
    const char* pB = (const char*)(smem + 16384 + (t & 1) * 4096);
#pragma unroll
    for (int ks = 0; ks < 2; ++ks) {
      const int kb = ks * 64 + ((lane >> 4) << 4);
      bf16x8 af[4], bfg[2];
#pragma unroll
      for (int i = 0; i < 4; ++i) {
        int r = wm * 64 + i * 16 + (lane & 15);
        af[i] = *(const bf16x8*)(pA + r * 128 + (kb ^ ((r & 7) << 4)));
      }
#pragma unroll
      for (int j = 0; j < 2; ++j) {
        int c = wn * 32 + j * 16 + (lane & 15);
        bfg[j] = *(const bf16x8*)(pB + c * 128 + (kb ^ ((c & 7) << 4)));
      }
#pragma unroll
      for (int i = 0; i < 4; ++i)
#pragma unroll
        for (int j = 0; j < 2; ++j)
          acc[i][j] = __builtin_amdgcn_mfma_f32_16x16x32_bf16(af[i], bfg[j], acc[i][j], 0, 0, 0);
    }
    asm volatile("s_waitcnt lgkmcnt(0)" ::: "memory");
    __builtin_amdgcn_s_barrier();
    if (t + 2 < nt_k) stage(t & 1, (t + 2) * 64);
  }

#pragma unroll
  for (int i = 0; i < 4; ++i) {
    const int mrow = m0 + wm * 64 + i * 16 + ((lane >> 4) << 2);
    const int b = mrow >> 12, s = mrow & 4095;
#pragma unroll
    for (int j = 0; j < 2; ++j) {
      const int n = n0 + wn * 32 + j * 16 + (lane & 15);
      const size_t off = ((size_t)(b * 1280 + n) << 12) + s;
      const float bs = bias[n];
      const float4 xr = *(const float4*)(xres + off);
      float4 o;
      o.x = acc[i][j][0] + bs + xr.x;
      o.y = acc[i][j][1] + bs + xr.y;
      o.z = acc[i][j][2] + bs + xr.z;
      o.w = acc[i][j][3] + bs + xr.w;
      *(float4*)(dout + off) = o;
    }
  }
}

// ---------------- split-K reduce for merged K/V projections (float4) ---------
__global__ __launch_bounds__(256) void k_kv_reduce(
    const float* __restrict__ part, const float* __restrict__ bk,
    const float* __restrict__ bv, bf16_t* __restrict__ kb, bf16_t* __restrict__ vb)
{
  const int i4 = (blockIdx.x * 256 + threadIdx.x) * 4;
  if (i4 >= 154 * 2560) return;
  const int r = i4 / 2560, n = i4 % 2560;
  float4 s = (n < 1280) ? *(const float4*)(bk + n) : *(const float4*)(bv + n - 1280);
#pragma unroll
  for (int sp = 0; sp < 8; ++sp) {
    float4 p = *(const float4*)(part + (size_t)sp * (154 * 2560) + i4);
    s.x += p.x; s.y += p.y; s.z += p.z; s.w += p.w;
  }
  bf16_t* dst = (n < 1280) ? (kb + (size_t)r * 1280 + n) : (vb + (size_t)r * 1280 + n - 1280);
  dst[0] = (bf16_t)s.x; dst[1] = (bf16_t)s.y; dst[2] = (bf16_t)s.z; dst[3] = (bf16_t)s.w;
}

// ---------------- fused attention (per head, per 64-row s tile) ----------------
__global__ __launch_bounds__(256) void k_attn(
    const bf16_t* __restrict__ q, const bf16_t* __restrict__ kbuf,
    const bf16_t* __restrict__ vbuf, bf16_t* __restrict__ ao,
    const float* __restrict__ size_reg, const int* __restrict__ mask,
    const float* __restrict__ treg)
{
  __shared__ alignas(16) bf16_t sQ[64 * 64];
  __shared__ alignas(16) bf16_t sK[80 * 64];
  __shared__ alignas(16) bf16_t sVT[64 * 104];
  __shared__ alignas(16) bf16_t sP[4 * 16 * 104];
  const int s0   = blockIdx.x * 64;
  const int bh   = blockIdx.y;
  const int b    = bh / 20, head = bh % 20;
  const int tid  = threadIdx.x, lane = tid & 63, wv = tid >> 6;
  const int ntok = lane & 15;

  const u32x4 uz = {0u, 0u, 0u, 0u};
  for (int i = tid; i < 832; i += 256) ((u32x4*)sVT)[i] = uz;
  for (int i = tid; i < 832; i += 256) ((u32x4*)sP)[i]  = uz;

  const size_t qbase = ((size_t)(b * 4096 + s0)) * 1280 + head * 64;
  for (int slot = tid; slot < 512; slot += 256) {
    int row = slot >> 3, ch = slot & 7;
    u32x4 d = *(const u32x4*)(q + qbase + (size_t)row * 1280 + ((ch ^ (row & 7)) << 3));
    *(u32x4*)((char*)sQ + slot * 16) = d;
  }
  const size_t kvbase = ((size_t)(b * 77)) * 1280 + head * 64;
  for (int slot = tid; slot < 640; slot += 256) {
    int tok = slot >> 3, ch = slot & 7;
    u32x4 d = uz;
    if (tok < 77)
      d = *(const u32x4*)(kbuf + kvbase + (size_t)tok * 1280 + ((ch ^ (tok & 7)) << 3));
    *(u32x4*)((char*)sK + slot * 16) = d;
  }
  __syncthreads();
  for (int e = tid; e < 77 * 64; e += 256) {
    int tok = e >> 6, dh = e & 63;
    sVT[dh * 104 + tok] = vbuf[kvbase + (size_t)tok * 1280 + dh];
  }
  __syncthreads();

  f32x4 sim[5];
  const f32x4 fz = {0.f, 0.f, 0.f, 0.f};
#pragma unroll
  for (int nf = 0; nf < 5; ++nf) sim[nf] = fz;
  const int qrow = wv * 16 + (lane & 15);
#pragma unroll
  for (int ks = 0; ks < 2; ++ks) {
    const int kb = ks * 64 + ((lane >> 4) << 4);
    bf16x8 aq = *(const bf16x8*)((const char*)sQ + qrow * 128 + (kb ^ ((qrow & 7) << 4)));
#pragma unroll
    for (int nf = 0; nf < 5; ++nf) {
      int tok = nf * 16 + ntok;
      bf16x8 bk = *(const bf16x8*)((const char*)sK + tok * 128 + (kb ^ ((tok & 7) << 4)));
      sim[nf] = __builtin_amdgcn_mfma_f32_16x16x32_bf16(aq, bk, sim[nf], 0, 0, 0);
    }
  }

  float vv[5][4];
#pragma unroll
  for (int nf = 0; nf < 5; ++nf)
#pragma unroll
    for (int r = 0; r < 4; ++r) vv[nf][r] = sim[nf][r] * 0.125f;

  const int rbase = s0 + wv * 16 + ((lane >> 4) << 2);

  if (b == 1) {
    const float tr = treg[0];
#pragma unroll
    for (int r = 0; r < 4; ++r) {
      float mx = -1e30f, mn = 1e30f;
#pragma unroll
      for (int nf = 0; nf < 5; ++nf)
        if (nf * 16 + ntok < 77) { mx = fmaxf(mx, vv[nf][r]); mn = fminf(mn, vv[nf][r]); }
#pragma unroll
      for (int m = 1; m < 16; m <<= 1) {
        mx = fmaxf(mx, __shfl_xor(mx, m));
        mn = fminf(mn, __shfl_xor(mn, m));
      }
      const int srow = rbase + r;
#pragma unroll
      for (int nf = 0; nf < 5; ++nf) {
        int l = nf * 16 + ntok;
        if (l < 77) {
          float w  = size_reg[srow * 77 + l] * tr;
          int   mk = mask[srow * 77 + l];
          float v  = vv[nf][r];
          vv[nf][r] = (mk > 0) ? v + w * (mx - v) : v - w * (v - mn);
        }
      }
    }
  }

#pragma unroll
  for (int r = 0; r < 4; ++r) {
    float mx = -1e30f;
#pragma unroll
    for (int nf = 0; nf < 5; ++nf)
      if (nf * 16 + ntok < 77) mx = fmaxf(mx, vv[nf][r]);
#pragma unroll
    for (int m = 1; m < 16; m <<= 1) mx = fmaxf(mx, __shfl_xor(mx, m));
    float p[5]; float sm = 0.f;
#pragma unroll
    for (int nf = 0; nf < 5; ++nf) {
      bool val = (nf * 16 + ntok) < 77;
      p[nf] = val ? __expf(vv[nf][r] - mx) : 0.f;
      sm += p[nf];
    }
#pragma unroll
    for (int m = 1; m < 16; m <<= 1) sm += __shfl_xor(sm, m);
    const float inv = 1.0f / sm;
    const int prow = ((lane >> 4) << 2) + r;
#pragma unroll
    for (int nf = 0; nf < 5; ++nf)
      sP[wv * 1664 + prow * 104 + nf * 16 + ntok] = (bf16_t)(p[nf] * inv);
  }
  __syncthreads();

  f32x4 o[4];
#pragma unroll
  for (int fd = 0; fd < 4; ++fd) o[fd] = fz;
#pragma unroll
  for (int ks = 0; ks < 3; ++ks) {
    const int kb = ks * 64 + ((lane >> 4) << 4);
    bf16x8 ap = *(const bf16x8*)((const char*)sP + wv * 3328 + (lane & 15) * 208 + kb);
#pragma unroll
    for (int fd = 0; fd < 4; ++fd) {
      bf16x8 bv = *(const bf16x8*)((const char*)sVT + (fd * 16 + (lane & 15)) * 208 + kb);
      o[fd] = __builtin_amdgcn_mfma_f32_16x16x32_bf16(ap, bv, o[fd], 0, 0, 0);
    }
  }
  const size_t obase =
      ((size_t)(b * 4096 + s0 + wv * 16 + ((lane >> 4) << 2))) * 1280 + head * 64;
#pragma unroll
  for (int fd = 0; fd < 4; ++fd)
#pragma unroll
    for (int r = 0; r < 4; ++r)
      ao[obase + (size_t)r * 1280 + fd * 16 + (lane & 15)] = (bf16_t)o[fd][r];
}

// ---------------- host launch ----------------
extern "C" void kernel_launch(void* const* d_in, const int* in_sizes, int n_in,
                              void* d_out, int out_size, void* d_ws, size_t ws_size,
                              hipStream_t stream)
{
  const float* x    = (const float*)d_in[0];
  const float* text = (const float*)d_in[1];
  const float* gng  = (const float*)d_in[2];
  const float* gnb  = (const float*)d_in[3];
  const float* lng  = (const float*)d_in[4];
  const float* lnb  = (const float*)d_in[5];
  const float* Wq   = (const float*)d_in[6];
  const float* bq   = (const float*)d_in[7];
  const float* Wk   = (const float*)d_in[8];
  const float* bk   = (const float*)d_in[9];
  const float* Wv   = (const float*)d_in[10];
  const float* bv   = (const float*)d_in[11];
  const float* Wo   = (const float*)d_in[12];
  const float* bo   = (const float*)d_in[13];
  const float* sreg = (const float*)d_in[14];
  const float* treg = (const float*)d_in[15];
  const int*   msk  = (const int*)d_in[16];
  float* out = (float*)d_out;

  char* ws = (char*)d_ws;
  size_t off = 0;
  auto alloc = [&](size_t bytes) {
    char* p = ws + off;
    off += (bytes + 255) & ~(size_t)255;
    return p;
  };
  float*  partial = (float*)alloc(2048 * 2 * sizeof(float));
  bf16_t* WqT = (bf16_t*)alloc((size_t)1280 * 1280 * 2);
  bf16_t* WkT = (bf16_t*)alloc((size_t)1280 * 4096 * 2);  // WvT contiguous after
  bf16_t* WvT = (bf16_t*)alloc((size_t)1280 * 4096 * 2);
  bf16_t* WoT = (bf16_t*)alloc((size_t)1280 * 1280 * 2);
  bf16_t* h   = (bf16_t*)alloc((size_t)8192 * 1280 * 2);  // reused as attn_out
  bf16_t* enc = (bf16_t*)alloc((size_t)154 * 4096 * 2);
  bf16_t* qb  = (bf16_t*)alloc((size_t)8192 * 1280 * 2);
  bf16_t* kb  = (bf16_t*)alloc((size_t)154 * 1280 * 2);
  bf16_t* vb  = (bf16_t*)alloc((size_t)154 * 1280 * 2);
  float*  part = (float*)alloc((size_t)8 * 154 * 2560 * sizeof(float));

  // prep: 4 weight transposes + gn_partial + layernorm in ONE launch
  k_prep<<<8922, 256, 0, stream>>>(x, text, lng, lnb, Wq, Wo, Wk, Wv,
                                   WqT, WoT, WkT, WvT, partial, enc);

  // gn apply (finalize fused)
  k_gn_apply<<<dim3(64, 20, 2), 256, 0, stream>>>(x, partial, gng, gnb, h);

  // merged Q-proj (1280 blocks) + K/V-proj split-K (640 blocks)
  k_gemm_qkv<<<dim3(1920), 256, 0, stream>>>(h, WqT, bq, qb, enc, WkT, part);
  k_kv_reduce<<<385, 256, 0, stream>>>(part, bk, bv, kb, vb);

  // attention (writes attn_out into h buffer)
  k_attn<<<dim3(64, 40), 256, 0, stream>>>(qb, kb, vb, h, sreg, msk, treg);

  // output projection + residual + transpose to (B,C,S)
  k_gemm_o<<<dim3(1280), 256, 0, stream>>>(h, WoT, bo, x, out);
}